// Round 4
// baseline (12470.593 us; speedup 1.0000x reference)
//
#include <hip/hip_runtime.h>

#define NB 128
#define NT 512
#define NE 256
#define NH 512
#define NA 64
#define NG 8
#define GB 16

typedef short bf16x8 __attribute__((ext_vector_type(8)));
typedef float f32x4 __attribute__((ext_vector_type(4)));
typedef unsigned short u16x8 __attribute__((ext_vector_type(8)));
typedef unsigned u32x4 __attribute__((ext_vector_type(4)));
typedef unsigned long long u64;

#define TAGFF 0xFFFFFFFFFFFFFFFFull

__device__ __forceinline__ unsigned short f2bf(float f){
  unsigned u = __builtin_bit_cast(unsigned, f);
  u = u + 0x7fffu + ((u >> 16) & 1u);
  return (unsigned short)(u >> 16);
}
__device__ __forceinline__ float bf2f(unsigned short h){
  unsigned u = ((unsigned)h) << 16;
  return __builtin_bit_cast(float, u);
}
__device__ __forceinline__ bf16x8 packbf2(f32x4 a, f32x4 b){
  bf16x8 r;
  r[0]=(short)f2bf(a[0]); r[1]=(short)f2bf(a[1]); r[2]=(short)f2bf(a[2]); r[3]=(short)f2bf(a[3]);
  r[4]=(short)f2bf(b[0]); r[5]=(short)f2bf(b[1]); r[6]=(short)f2bf(b[2]); r[7]=(short)f2bf(b[3]);
  return r;
}
__device__ __forceinline__ bf16x8 loadB_f32(const float* p){
  f32x4 a = *(const f32x4*)p;
  f32x4 b = *(const f32x4*)(p + 4);
  return packbf2(a, b);
}
#define MFMA(a,b,c) __builtin_amdgcn_mfma_f32_16x16x32_bf16(a,b,c,0,0,0)

__device__ __forceinline__ float fsig(float x){
  return __builtin_amdgcn_rcpf(1.f + __expf(-x));
}
__device__ __forceinline__ float ftanh(float x){
  float e2 = __expf(2.f * x);
  return 1.f - 2.f * __builtin_amdgcn_rcpf(e2 + 1.f);
}

// ---- seq-tagged slot protocol, two transports ----
// unit u64 = {seq:32 | payload}. Producers fire (atomic exchange, result
// discarded); consumers poll the data until tags match.
//  MALL path: agent-scope atomics (die-level coherence point) -- correct for
//    ANY workgroup placement. Proven in rounds 0-2.
//  L2 path: workgroup-scope atomics -- atomics always execute at the XCD's
//    TCC/L2, so co-XCD workgroups are coherent through it at ~4x lower RT.
//    Selected ONLY after a bounded functional probe proves the transport for
//    this group; polls pair an sc0 bulk load with an atomic-RMW(+0) retry so
//    forward progress never depends on load-flag semantics.
__device__ __forceinline__ u64 aload(const u64* p){
  return __hip_atomic_load(p, __ATOMIC_RELAXED, __HIP_MEMORY_SCOPE_AGENT);
}
__device__ __forceinline__ void fire(u64* p, u64 v){
  (void)__hip_atomic_exchange(p, v, __ATOMIC_RELAXED, __HIP_MEMORY_SCOPE_AGENT);
}
__device__ __forceinline__ void fire_f(u64* p, u64 v){
  (void)__hip_atomic_exchange(p, v, __ATOMIC_RELAXED, __HIP_MEMORY_SCOPE_WORKGROUP);
}
__device__ __forceinline__ u64 rmw0(u64* p){
  return __hip_atomic_fetch_add(p, 0ull, __ATOMIC_RELAXED, __HIP_MEMORY_SCOPE_WORKGROUP);
}
__device__ __forceinline__ void load4_sc0(const u64* p, u64& x0, u64& x1, u64& x2, u64& x3){
  u32x4 a, b;
  asm volatile("global_load_dwordx4 %0, %2, off sc0\n\t"
               "global_load_dwordx4 %1, %2, off offset:16 sc0\n\t"
               "s_waitcnt vmcnt(0)"
               : "=&v"(a), "=&v"(b) : "v"(p) : "memory");
  x0 = ((u64)a[1]<<32)|a[0]; x1 = ((u64)a[3]<<32)|a[2];
  x2 = ((u64)b[1]<<32)|b[0]; x3 = ((u64)b[3]<<32)|b[2];
}
__device__ __forceinline__ u64 load1_sc0(const u64* p){
  u64 x;
  asm volatile("global_load_dwordx2 %0, %1, off sc0\n\t"
               "s_waitcnt vmcnt(0)"
               : "=&v"(x) : "v"(p) : "memory");
  return x;
}
__device__ __forceinline__ u64 packh(unsigned sq, float a, float b){
  return ((u64)sq << 32) | ((u64)f2bf(b) << 16) | (u64)f2bf(a);
}
__device__ __forceinline__ u64 packf(unsigned sq, float a){
  return ((u64)sq << 32) | (u64)__builtin_bit_cast(unsigned, a);
}

// ---------------------------------------------------------------------------
// Pre-pass: tp[pos][a] = (embedding[token] . Wt[a,:]) + bt[a], stored bf16.
// ---------------------------------------------------------------------------
__global__ __launch_bounds__(256) void k_tp(
    const int* __restrict__ tok, const float* __restrict__ emb,
    const float* __restrict__ Wt, const float* __restrict__ bt,
    unsigned short* __restrict__ tp)
{
  const int lane = threadIdx.x & 63;
  const int w = threadIdx.x >> 6;
  const int m16 = lane & 15, quad = lane >> 4;

  bf16x8 wfq[8][4];
#pragma unroll
  for (int kc = 0; kc < 8; kc++)
#pragma unroll
    for (int nt = 0; nt < 4; nt++)
      wfq[kc][nt] = loadB_f32(Wt + (nt*16 + m16)*NE + kc*32 + quad*8);

  float btv[4];
#pragma unroll
  for (int nt = 0; nt < 4; nt++) btv[nt] = bt[nt*16 + m16];

  const int gw = blockIdx.x * 4 + w;
#pragma unroll 1
  for (int it = 0; it < 4; it++){
    const int pt = gw * 4 + it;
    const int pos = pt*16 + m16;
    const long row = (long)tok[pos];
    const float* xrow = emb + row * NE;
    f32x4 acc[4] = {{0,0,0,0},{0,0,0,0},{0,0,0,0},{0,0,0,0}};
#pragma unroll
    for (int kc = 0; kc < 8; kc++){
      bf16x8 af = loadB_f32(xrow + kc*32 + quad*8);
#pragma unroll
      for (int nt = 0; nt < 4; nt++)
        acc[nt] = MFMA(af, wfq[kc][nt], acc[nt]);
    }
#pragma unroll
    for (int nt = 0; nt < 4; nt++)
#pragma unroll
      for (int r = 0; r < 4; r++){
        int posr = pt*16 + quad*4 + r;
        tp[(long)posr * NA + nt*16 + m16] = f2bf(acc[nt][r] + btv[nt]);
      }
  }
}

// ---------------------------------------------------------------------------
// Pre-pass 2: pack Wq blob; bump the per-launch nonce (not memset: survives
// graph replay, +1 per launch, so stale probe lines can never match).
// ---------------------------------------------------------------------------
__global__ __launch_bounds__(256) void k_pack(
    const float* __restrict__ Wq, unsigned short* __restrict__ blob, u64* nonce)
{
  if (threadIdx.x == 0)
    (void)__hip_atomic_fetch_add(nonce, 1ull, __ATOMIC_RELAXED, __HIP_MEMORY_SCOPE_AGENT);
  const int lane = threadIdx.x & 63, wv = threadIdx.x >> 6;
  const int m16 = lane & 15, quad = lane >> 4;
#pragma unroll
  for (int kc = 0; kc < 16; kc++){
    bf16x8 t = loadB_f32(Wq + (long)(wv*16 + m16)*NH + kc*32 + quad*8);
    *(bf16x8*)&blob[((wv*16 + kc)*64 + lane)*8] = t;
  }
}

// ---------------------------------------------------------------------------
struct KArgs {
  const int* len;
  const float* bq; const float* v; const float* bv;
  const float* Wih0; const float* Whh0; const float* bih0; const float* bhh0;
  const float* Wih1; const float* Whh1; const float* bih1; const float* bhh1;
  const unsigned short* tp;
  const unsigned short* wqblob;
  u64* hbuf;   // per group: [state*2+par][4096] u64; unit idx(dp,b)=(dp>>2)*64+b*4+(dp&3)
  u64* cbuf;   // per group: [par][half][16 batch][72] u64
  u64* ptab;   // probe slots [g][m]
  u64* vt1;    // verdict table [g][m]
  u64* vt2;    // rendezvous table [g][m]
  u64* nonce;
  float* out;
};

// Poll+stage a 512x16 bf16 h-state into fragment-ordered LDS [kc][lane][8].
// Per-thread: 4 contiguous u64 (one 32B segment). Detection overlaps transfer.
__device__ __forceinline__ void stage_load(u64* __restrict__ buf, unsigned sq,
                                           unsigned short (*hs)[64][8], int tid, bool fast){
  const int lane = tid & 63, wv = tid >> 6;
  const int b = lane & 15, q8 = lane >> 4;
#pragma unroll
  for (int c = 0; c < 4; c++){
    const int kc = wv*4 + c;
    u64* u0 = buf + (kc*4 + q8)*64 + b*4;
    u64 x0, x1, x2, x3;
    if (fast){
      for (;;){
        load4_sc0(u0, x0, x1, x2, x3);
        if ((unsigned)(x0>>32)==sq && (unsigned)(x1>>32)==sq &&
            (unsigned)(x2>>32)==sq && (unsigned)(x3>>32)==sq) break;
        // RMW retry executes at the L2 point: progress even if sc0 reads stale
        x0 = rmw0(u0);     x1 = rmw0(u0 + 1);
        x2 = rmw0(u0 + 2); x3 = rmw0(u0 + 3);
        if ((unsigned)(x0>>32)==sq && (unsigned)(x1>>32)==sq &&
            (unsigned)(x2>>32)==sq && (unsigned)(x3>>32)==sq) break;
        __builtin_amdgcn_s_sleep(1);
      }
    } else {
      for (;;){
        x0 = aload(u0);     x1 = aload(u0 + 1);
        x2 = aload(u0 + 2); x3 = aload(u0 + 3);
        if ((unsigned)(x0>>32)==sq && (unsigned)(x1>>32)==sq &&
            (unsigned)(x2>>32)==sq && (unsigned)(x3>>32)==sq) break;
        __builtin_amdgcn_s_sleep(1);
      }
    }
    u16x8 d;
    d[0]=(unsigned short)x0; d[1]=(unsigned short)(x0>>16);
    d[2]=(unsigned short)x1; d[3]=(unsigned short)(x1>>16);
    d[4]=(unsigned short)x2; d[5]=(unsigned short)(x2>>16);
    d[6]=(unsigned short)x3; d[7]=(unsigned short)(x3>>16);
    *(u16x8*)&hs[kc][lane][0] = d;
  }
}

__global__ __launch_bounds__(256, 1) void k_main(KArgs A_)
{
  const int tid = threadIdx.x, lane = tid & 63, w = tid >> 6;
  const int g = blockIdx.x & 7, m = blockIdx.x >> 3;   // group, member
  const int m16 = lane & 15, quad = lane >> 4;

  __shared__ __attribute__((aligned(16))) unsigned short h0s[16][64][8]; // 16KB
  __shared__ __attribute__((aligned(16))) unsigned short h1s[16][64][8]; // 16KB
  __shared__ __attribute__((aligned(16))) float dslab[6][256];           // gate staging
  __shared__ __attribute__((aligned(16))) float qs[16][68];              // q[b][a]
  __shared__ __attribute__((aligned(16))) float cslab[4][64];            // per-wave ctx partials
  __shared__ float cden[4];
  __shared__ __attribute__((aligned(16))) unsigned short ctxf[64][16];   // scaled ctx B-frags
  __shared__ int fastflag;

  u64* hb  = A_.hbuf + (long)g * (4*4096);       // [h0 p0|h0 p1|h1 p0|h1 p1]
  u64* cb  = A_.cbuf + (long)g * (2*2*16*72);    // [par][half][b][72]
  u64* pt  = A_.ptab + g*32;
  u64* vt1 = A_.vt1  + g*32;
  u64* vt2 = A_.vt2  + g*32;
  const int b0 = g * GB;

  // ----- persistent weight fragments (w<3): wf[0..15]=Whh0, [16..31]=Whh1,
  //       [32..47]=Wih1, rows w*512 + m*16 -----
  bf16x8 wf[48], wih0f[2];
  float bhh0v[4], bih0v[4], bhh1v[4], bih1v[4];
  if (w < 3){
    const int r0 = w * NH + m * 16;
#pragma unroll
    for (int kc = 0; kc < 16; kc++){
      wf[kc]    = loadB_f32(A_.Whh0 + (long)(r0 + m16)*NH + kc*32 + quad*8);
      wf[16+kc] = loadB_f32(A_.Whh1 + (long)(r0 + m16)*NH + kc*32 + quad*8);
      wf[32+kc] = loadB_f32(A_.Wih1 + (long)(r0 + m16)*NH + kc*32 + quad*8);
    }
#pragma unroll
    for (int kc = 0; kc < 2; kc++)
      wih0f[kc] = loadB_f32(A_.Wih0 + (r0 + m16)*NA + kc*32 + quad*8);
#pragma unroll
    for (int r = 0; r < 4; r++){
      int d = r0 + quad*4 + r;
      bhh0v[r] = A_.bhh0[d]; bih0v[r] = A_.bih0[d];
      bhh1v[r] = A_.bhh1[d]; bih1v[r] = A_.bih1[d];
    }
  }
  float bqw[4];
#pragma unroll
  for (int r = 0; r < 4; r++) bqw[r] = A_.bq[w*16 + quad*4 + r];

  float vv[16];
#pragma unroll
  for (int jj = 0; jj < 16; jj++) vv[jj] = A_.v[quad*16 + jj];
  const float bvv = A_.bv[0];
  const int ab = m >> 1;            // batch owned by WG pair {2ab, 2ab+1}
  const int wr = (m & 1)*4 + w;     // chunk phase 0..7

  int myidx = 0, imax = 0;
#pragma unroll 1
  for (int b = 0; b < GB; b++){
    int L = A_.len[b0 + b];
    int ix = L - 2; ix = ix < 0 ? 0 : (ix > NT-1 ? NT-1 : ix);
    if (b == m16) myidx = ix;
    imax = imax > ix ? imax : ix;
  }

  f32x4 h0p = {0,0,0,0}, h1p = {0,0,0,0};

  // zero LDS h-state so step 0's matmuls yield pure bias (h(-1)=0)
  {
    u16x8 z = {0,0,0,0,0,0,0,0};
#pragma unroll
    for (int c = 0; c < 4; c++){
      int kc = (tid>>6)*4 + c;
      *(u16x8*)&h0s[kc][lane][0] = z;
      *(u16x8*)&h1s[kc][lane][0] = z;
    }
  }

  // ================= transport selection =================
  // Bounded functional probe of the L2 transport (nonce-tagged, 3 rounds so
  // round>=2 re-reads lines already touched -> detects any staleness), then a
  // MALL-published global verdict. Any failure -> all 32 members take the
  // proven MALL protocol. Performance-only use of WG placement.
  if (tid == 0){
    const u64 nn = aload(A_.nonce);
    int ok = 1;
    for (int r = 1; r <= 3 && ok; r++){
      fire_f(pt + m, (nn << 16) | (unsigned)(r*64 + m));
      for (int j = 0; j < 32 && ok; j++){
        const u64 want = (nn << 16) | (unsigned)(r*64 + j);
        int cnt = 0;
        while (rmw0(pt + j) != want){
          if (++cnt > 20000){ ok = 0; break; }
          __builtin_amdgcn_s_sleep(4);
        }
      }
    }
    fire(vt1 + m, ok ? 1ull : 2ull);
    int allok = 1;
    for (int j = 0; j < 32; j++){
      u64 v;
      while ((v = aload(vt1 + j)) == 0) __builtin_amdgcn_s_sleep(2);
      allok &= (v == 1ull);
    }
    fastflag = allok;
  }
  __syncthreads();
  const bool fast = (fastflag != 0);

  if (fast){
    // init this group's slots THROUGH the L2 transport (so local-L2 reads see
    // the poison regardless of what previous iterations left dirty here)
    fire_f(hb + m*512 + tid*2 + 0, TAGFF);
    fire_f(hb + m*512 + tid*2 + 1, TAGFF);
    if (tid < 144) fire_f(cb + m*144 + tid, TAGFF);
    __syncthreads();
    if (tid == 0){   // rendezvous: nobody fires real data before all init done
      fire(vt2 + m, 1ull);
      for (int j = 0; j < 32; j++)
        while (aload(vt2 + j) == 0) __builtin_amdgcn_s_sleep(2);
    }
    __syncthreads();
  }

#pragma unroll 1
  for (int i = 0; i <= imax; i++){
    const int par = i & 1;
    const unsigned sq = (unsigned)(i + 1);

    // ============ Phase A: stage h1(i-1); q rows w*16 (all waves) ============
    if (i > 0){
      stage_load(hb + (long)(2 + ((i-1)&1))*4096, (unsigned)i, h1s, tid, fast);
      __syncthreads();
    }
    {
      f32x4 qa = {0,0,0,0};
#pragma unroll
      for (int kc = 0; kc < 16; kc++){
        bf16x8 b1f = *(const bf16x8*)&h1s[kc][lane][0];
        bf16x8 af = *(const bf16x8*)&A_.wqblob[((w*16 + kc)*64 + lane)*8];
        qa = MFMA(af, b1f, qa);
      }
#pragma unroll
      for (int r = 0; r < 4; r++)
        qs[m16][w*16 + quad*4 + r] = qa[r] + bqw[r];
    }
    __syncthreads();   // q ready in LDS

    // ============ Phase B: attention for batch ab, chunk phase wr ============
    {
      float qv[16];
#pragma unroll
      for (int jq = 0; jq < 4; jq++){
        f32x4 t = *(const f32x4*)&qs[ab][quad*16 + jq*4];
        qv[jq*4+0]=t[0]; qv[jq*4+1]=t[1]; qv[jq*4+2]=t[2]; qv[jq*4+3]=t[3];
      }
      float ctxp[16];
#pragma unroll
      for (int jj = 0; jj < 16; jj++) ctxp[jj] = 0.f;
      float denp = 0.f;
      const unsigned short* tpb = A_.tp + (long)(b0 + ab) * NT * NA;
#pragma unroll 1
      for (int c = wr; c*16 <= i; c += 8){
        const int t = c*16 + m16;
        const unsigned short* tpp = tpb + (long)t*NA + quad*16;
        u16x8 ta = *(const u16x8*)tpp;
        u16x8 tb = *(const u16x8*)(tpp + 8);
        float tpf[16];
#pragma unroll
        for (int jj = 0; jj < 8; jj++){ tpf[jj] = bf2f(ta[jj]); tpf[8+jj] = bf2f(tb[jj]); }
        float sp = 0.f;
#pragma unroll
        for (int jj = 0; jj < 16; jj++){
          float x = tpf[jj] + qv[jj];
          sp = fmaf(ftanh(x), vv[jj], sp);
        }
        sp += __shfl_xor(sp, 16);
        sp += __shfl_xor(sp, 32);
        float e = __expf(sp + bvv);
        e = (t <= i) ? e : 0.f;
        denp += e;
#pragma unroll
        for (int jj = 0; jj < 16; jj++) ctxp[jj] = fmaf(e, tpf[jj], ctxp[jj]);
      }
#pragma unroll
      for (int off = 1; off < 64; off <<= 1) denp += __shfl_xor(denp, off);
      denp *= 0.25f;
#pragma unroll
      for (int st = 0; st < 4; st++){
        const int bit = 1 << st;
        const bool up = (lane >> st) & 1;
        const int n2 = (16 >> st) >> 1;
#pragma unroll
        for (int j2 = 0; j2 < 8; j2++){
          if (j2 < n2){
            float keep = up ? ctxp[2*j2+1] : ctxp[2*j2];
            float send = up ? ctxp[2*j2]   : ctxp[2*j2+1];
            float got = __shfl_xor(send, bit);
            ctxp[j2] = keep + got;
          }
        }
      }
      cslab[w][lane] = ctxp[0];
      if (lane == 0) cden[w] = denp;
    }
    __syncthreads();   // 4-wave partials in LDS
    if (w == 0){
      float s = cslab[0][lane] + cslab[1][lane] + cslab[2][lane] + cslab[3][lane];
      u64* slot = cb + ((long)(par*2 + (m & 1))*16 + ab)*72;
      u64 du = packf(sq, s);
      u64 dd = packf(sq, cden[0]+cden[1]+cden[2]+cden[3]);
      if (fast){
        fire_f(slot + lane, du);
        if (lane == 0) fire_f(slot + 64, dd);
      } else {
        fire(slot + lane, du);
        if (lane == 0) fire(slot + 64, dd);
      }
    }

    // ============ Phase C: w3 polls ctx; w<3 overlap gh1 + gh0 matmuls ========
    f32x4 gh1 = {0,0,0,0}, g0 = {0,0,0,0};
    if (w < 3){
#pragma unroll
      for (int kc = 0; kc < 16; kc++){
        bf16x8 b1f = *(const bf16x8*)&h1s[kc][lane][0];
        gh1 = MFMA(wf[16+kc], b1f, gh1);
        bf16x8 h0f = *(const bf16x8*)&h0s[kc][lane][0];
        g0  = MFMA(wf[kc], h0f, g0);
      }
#pragma unroll
      for (int r = 0; r < 4; r++){ gh1[r] += bhh1v[r]; g0[r] += bhh0v[r]; }
    } else {
      u64* c0 = cb + ((long)(par*2 + 0)*16 + m16)*72;
      u64* c1 = cb + ((long)(par*2 + 1)*16 + m16)*72;
      u64 d0, d1;
      if (fast){
        for (;;){
          d0 = load1_sc0(c0 + 64); d1 = load1_sc0(c1 + 64);
          if ((unsigned)(d0>>32)==sq && (unsigned)(d1>>32)==sq) break;
          d0 = rmw0(c0 + 64); d1 = rmw0(c1 + 64);
          if ((unsigned)(d0>>32)==sq && (unsigned)(d1>>32)==sq) break;
          __builtin_amdgcn_s_sleep(1);
        }
      } else {
        for (;;){
          d0 = aload(c0 + 64); d1 = aload(c1 + 64);
          if ((unsigned)(d0>>32)==sq && (unsigned)(d1>>32)==sq) break;
          __builtin_amdgcn_s_sleep(1);
        }
      }
      const float rdn = __builtin_amdgcn_rcpf(
          __builtin_bit_cast(float,(unsigned)d0) + __builtin_bit_cast(float,(unsigned)d1));
#pragma unroll
      for (int kc = 0; kc < 2; kc++){
        const int a0 = kc*32 + quad*8;
        u64 t0[8], t1[8];
        if (fast){
          for (;;){
            bool ok = true;
            load4_sc0(c0 + a0,     t0[0], t0[1], t0[2], t0[3]);
            load4_sc0(c0 + a0 + 4, t0[4], t0[5], t0[6], t0[7]);
            load4_sc0(c1 + a0,     t1[0], t1[1], t1[2], t1[3]);
            load4_sc0(c1 + a0 + 4, t1[4], t1[5], t1[6], t1[7]);
#pragma unroll
            for (int j = 0; j < 8; j++)
              ok &= ((unsigned)(t0[j]>>32)==sq) & ((unsigned)(t1[j]>>32)==sq);
            if (ok) break;
            ok = true;
#pragma unroll
            for (int j = 0; j < 8; j++){
              t0[j] = rmw0(c0 + a0 + j); ok &= ((unsigned)(t0[j]>>32)==sq);
              t1[j] = rmw0(c1 + a0 + j); ok &= ((unsigned)(t1[j]>>32)==sq);
            }
            if (ok) break;
            __builtin_amdgcn_s_sleep(1);
          }
        } else {
          for (;;){
            bool ok = true;
#pragma unroll
            for (int j = 0; j < 8; j++){ t0[j] = aload(c0 + a0 + j); ok &= ((unsigned)(t0[j]>>32)==sq); }
#pragma unroll
            for (int j = 0; j < 8; j++){ t1[j] = aload(c1 + a0 + j); ok &= ((unsigned)(t1[j]>>32)==sq); }
            if (ok) break;
            __builtin_amdgcn_s_sleep(1);
          }
        }
        u16x8 f;
#pragma unroll
        for (int j = 0; j < 8; j++){
          float s = (__builtin_bit_cast(float,(unsigned)t0[j]) +
                     __builtin_bit_cast(float,(unsigned)t1[j])) * rdn;
          f[j] = f2bf(s);
        }
        *(u16x8*)&ctxf[lane][kc*8] = f;
      }
    }
    __syncthreads();   // ctx frags ready
    if (w < 3){
      f32x4 gi0 = {0,0,0,0};
      bf16x8 cf0 = *(const bf16x8*)&ctxf[lane][0];
      bf16x8 cf1 = *(const bf16x8*)&ctxf[lane][8];
      gi0 = MFMA(wih0f[0], cf0, gi0);
      gi0 = MFMA(wih0f[1], cf1, gi0);
#pragma unroll
      for (int r = 0; r < 4; r++) gi0[r] += bih0v[r];
      *(f32x4*)&dslab[w][lane*4] = g0;
      *(f32x4*)&dslab[3+w][lane*4] = gi0;
    }
    __syncthreads();
    if (w == 3){
      f32x4 ghr = *(f32x4*)&dslab[0][lane*4];
      f32x4 ghz = *(f32x4*)&dslab[1][lane*4];
      f32x4 ghn = *(f32x4*)&dslab[2][lane*4];
      f32x4 gir = *(f32x4*)&dslab[3][lane*4];
      f32x4 giz = *(f32x4*)&dslab[4][lane*4];
      f32x4 gin = *(f32x4*)&dslab[5][lane*4];
      f32x4 hn;
#pragma unroll
      for (int r = 0; r < 4; r++){
        float rr = fsig(gir[r] + ghr[r]);
        float zz = fsig(giz[r] + ghz[r]);
        float nn = ftanh(gin[r] + rr*ghn[r]);
        hn[r] = (1.f - zz)*nn + zz*h0p[r];
      }
      h0p = hn;
      const int dp0 = m*8 + quad*2;
      u64* p0 = hb + (long)par*4096 + (dp0>>2)*64 + m16*4 + (dp0&3);
      u64 va = packh(sq, hn[0], hn[1]);
      u64 vb = packh(sq, hn[2], hn[3]);
      if (fast){ fire_f(p0, va); fire_f(p0 + 1, vb); }
      else     { fire(p0, va);   fire(p0 + 1, vb); }
    }

    // ============ Phase D: stage h0(i); gi1; layer-1 combine ============
    stage_load(hb + (long)par*4096, sq, h0s, tid, fast);
    __syncthreads();
    if (w < 3){
      f32x4 gi1 = {0,0,0,0};
#pragma unroll
      for (int kc = 0; kc < 16; kc++){
        bf16x8 hf = *(const bf16x8*)&h0s[kc][lane][0];
        gi1 = MFMA(wf[32+kc], hf, gi1);
      }
#pragma unroll
      for (int r = 0; r < 4; r++) gi1[r] += bih1v[r];
      *(f32x4*)&dslab[w][lane*4] = gh1;
      *(f32x4*)&dslab[3+w][lane*4] = gi1;
    }
    __syncthreads();
    if (w == 3){
      f32x4 ghr = *(f32x4*)&dslab[0][lane*4];
      f32x4 ghz = *(f32x4*)&dslab[1][lane*4];
      f32x4 ghn = *(f32x4*)&dslab[2][lane*4];
      f32x4 gir = *(f32x4*)&dslab[3][lane*4];
      f32x4 giz = *(f32x4*)&dslab[4][lane*4];
      f32x4 gin = *(f32x4*)&dslab[5][lane*4];
      f32x4 hn;
#pragma unroll
      for (int r = 0; r < 4; r++){
        float rr = fsig(gir[r] + ghr[r]);
        float zz = fsig(giz[r] + ghz[r]);
        float nn = ftanh(gin[r] + rr*ghn[r]);
        hn[r] = (1.f - zz)*nn + zz*h1p[r];
      }
      h1p = hn;
      const int dp0 = m*8 + quad*2;
      u64* p1 = hb + (long)(2 + par)*4096 + (dp0>>2)*64 + m16*4 + (dp0&3);
      u64 va = packh(sq, hn[0], hn[1]);
      u64 vb = packh(sq, hn[2], hn[3]);
      if (fast){ fire_f(p1, va); fire_f(p1 + 1, vb); }
      else     { fire(p1, va);   fire(p1 + 1, vb); }
      if (i == myidx)
        *(f32x4*)&A_.out[(long)(b0 + m16)*NH + m*16 + quad*4] = hn;
    }
  }

  // fast-mode epilogue: after a group-wide rendezvous (all reads done),
  // re-poison this group's slots through the L2 transport so any later
  // eviction can only deposit inert 0xFF tags.
  if (fast){
    if (tid == 0){
      fire(vt2 + m, 2ull);
      for (int j = 0; j < 32; j++)
        while (aload(vt2 + j) < 2ull) __builtin_amdgcn_s_sleep(2);
    }
    __syncthreads();
    fire_f(hb + m*512 + tid*2 + 0, TAGFF);
    fire_f(hb + m*512 + tid*2 + 1, TAGFF);
    if (tid < 144) fire_f(cb + m*144 + tid, TAGFF);
  }
}

// ---------------------------------------------------------------------------
extern "C" void kernel_launch(void* const* d_in, const int* in_sizes, int n_in,
                              void* d_out, int out_size, void* d_ws, size_t ws_size,
                              hipStream_t stream)
{
  (void)in_sizes; (void)n_in; (void)out_size; (void)ws_size;
  char* ws = (char*)d_ws;
  unsigned short* tp     = (unsigned short*)ws;                    // 8 MB
  unsigned short* wqblob = (unsigned short*)(ws + 8388608);        // 64 KB
  u64* hbuf  = (u64*)(ws + 8388608 + 65536);                       // 1 MB
  u64* cbuf  = hbuf + 8 * (4*4096);                                // 288 KB
  u64* ptab  = cbuf + 8 * (2*2*16*72);                             // 2 KB
  u64* vt1   = ptab + 256;                                         // 2 KB
  u64* vt2   = vt1 + 256;                                          // 2 KB
  u64* nonce = vt2 + 256;                                          // 8 B (never memset)

  // 0xFF-fill data slots (tag 0xFFFFFFFF never matches a target seq <= 513);
  // zero the probe/verdict/rendezvous tables. nonce survives across launches.
  (void)hipMemsetAsync(hbuf, 0xFF, (size_t)(8*4*4096 + 8*2*2*16*72) * sizeof(u64), stream);
  (void)hipMemsetAsync(ptab, 0, (size_t)(3*256) * sizeof(u64), stream);

  k_tp<<<dim3(256), dim3(256), 0, stream>>>(
      (const int*)d_in[0], (const float*)d_in[2], (const float*)d_in[3],
      (const float*)d_in[4], tp);
  k_pack<<<dim3(1), dim3(256), 0, stream>>>((const float*)d_in[5], wqblob, nonce);

  KArgs ka;
  ka.len  = (const int*)d_in[1];
  ka.bq   = (const float*)d_in[6];
  ka.v    = (const float*)d_in[7];  ka.bv   = (const float*)d_in[8];
  ka.Wih0 = (const float*)d_in[9];  ka.Whh0 = (const float*)d_in[10];
  ka.bih0 = (const float*)d_in[11]; ka.bhh0 = (const float*)d_in[12];
  ka.Wih1 = (const float*)d_in[13]; ka.Whh1 = (const float*)d_in[14];
  ka.bih1 = (const float*)d_in[15]; ka.bhh1 = (const float*)d_in[16];
  ka.tp = tp; ka.wqblob = wqblob;
  ka.hbuf = hbuf; ka.cbuf = cbuf;
  ka.ptab = ptab; ka.vt1 = vt1; ka.vt2 = vt2; ka.nonce = nonce;
  ka.out = (float*)d_out;

  k_main<<<dim3(256), dim3(256), 0, stream>>>(ka);
}

// Round 6
// 6862.615 us; speedup vs baseline: 1.8172x; 1.8172x over previous
//
#include <hip/hip_runtime.h>

#define NB 128
#define NT 512
#define NE 256
#define NH 512
#define NA 64
#define NG 8
#define GB 16

typedef short bf16x8 __attribute__((ext_vector_type(8)));
typedef float f32x4 __attribute__((ext_vector_type(4)));
typedef unsigned short u16x8 __attribute__((ext_vector_type(8)));
typedef unsigned long long u64;

__device__ __forceinline__ unsigned short f2bf(float f){
  unsigned u = __builtin_bit_cast(unsigned, f);
  u = u + 0x7fffu + ((u >> 16) & 1u);
  return (unsigned short)(u >> 16);
}
__device__ __forceinline__ float bf2f(unsigned short h){
  unsigned u = ((unsigned)h) << 16;
  return __builtin_bit_cast(float, u);
}
__device__ __forceinline__ bf16x8 packbf2(f32x4 a, f32x4 b){
  bf16x8 r;
  r[0]=(short)f2bf(a[0]); r[1]=(short)f2bf(a[1]); r[2]=(short)f2bf(a[2]); r[3]=(short)f2bf(a[3]);
  r[4]=(short)f2bf(b[0]); r[5]=(short)f2bf(b[1]); r[6]=(short)f2bf(b[2]); r[7]=(short)f2bf(b[3]);
  return r;
}
__device__ __forceinline__ bf16x8 loadB_f32(const float* p){
  f32x4 a = *(const f32x4*)p;
  f32x4 b = *(const f32x4*)(p + 4);
  return packbf2(a, b);
}
#define MFMA(a,b,c) __builtin_amdgcn_mfma_f32_16x16x32_bf16(a,b,c,0,0,0)

__device__ __forceinline__ float fsig(float x){
  return __builtin_amdgcn_rcpf(1.f + __expf(-x));
}
__device__ __forceinline__ float ftanh(float x){
  float e2 = __expf(2.f * x);
  return 1.f - 2.f * __builtin_amdgcn_rcpf(e2 + 1.f);
}

// s_sleep needs a CONSTANT immediate: constant-ladder backoff.
// bk: 0,1,2,3+ -> sleep 1,2,4,8 (x64 cycles each).
__device__ __forceinline__ void sleep_bk(int bk){
  if (bk <= 0)      __builtin_amdgcn_s_sleep(1);
  else if (bk == 1) __builtin_amdgcn_s_sleep(2);
  else if (bk == 2) __builtin_amdgcn_s_sleep(4);
  else              __builtin_amdgcn_s_sleep(8);
}

// ---- MALL seq-tagged slot protocol (round-1 proven) ----
// unit u64 = {seq:32 | payload}. Producers fire-and-forget via agent-scope
// atomic exchange; consumers poll the data itself until tags match (detection
// overlaps transfer). Backoff keeps poll traffic off the LLC queues.
__device__ __forceinline__ u64 aload(const u64* p){
  return __hip_atomic_load(p, __ATOMIC_RELAXED, __HIP_MEMORY_SCOPE_AGENT);
}
__device__ __forceinline__ void fire(u64* p, u64 v){
  (void)__hip_atomic_exchange(p, v, __ATOMIC_RELAXED, __HIP_MEMORY_SCOPE_AGENT);
}
__device__ __forceinline__ u64 packh(unsigned sq, float a, float b){
  return ((u64)sq << 32) | ((u64)f2bf(b) << 16) | (u64)f2bf(a);
}
__device__ __forceinline__ u64 packf(unsigned sq, float a){
  return ((u64)sq << 32) | (u64)__builtin_bit_cast(unsigned, a);
}

// ---------------------------------------------------------------------------
// Pre-pass: tp[pos][a] = (embedding[token] . Wt[a,:]) + bt[a], stored bf16.
// ---------------------------------------------------------------------------
__global__ __launch_bounds__(256) void k_tp(
    const int* __restrict__ tok, const float* __restrict__ emb,
    const float* __restrict__ Wt, const float* __restrict__ bt,
    unsigned short* __restrict__ tp)
{
  const int lane = threadIdx.x & 63;
  const int w = threadIdx.x >> 6;
  const int m16 = lane & 15, quad = lane >> 4;

  bf16x8 wfq[8][4];
#pragma unroll
  for (int kc = 0; kc < 8; kc++)
#pragma unroll
    for (int nt = 0; nt < 4; nt++)
      wfq[kc][nt] = loadB_f32(Wt + (nt*16 + m16)*NE + kc*32 + quad*8);

  float btv[4];
#pragma unroll
  for (int nt = 0; nt < 4; nt++) btv[nt] = bt[nt*16 + m16];

  const int gw = blockIdx.x * 4 + w;
#pragma unroll 1
  for (int it = 0; it < 4; it++){
    const int pt = gw * 4 + it;
    const int pos = pt*16 + m16;
    const long row = (long)tok[pos];
    const float* xrow = emb + row * NE;
    f32x4 acc[4] = {{0,0,0,0},{0,0,0,0},{0,0,0,0},{0,0,0,0}};
#pragma unroll
    for (int kc = 0; kc < 8; kc++){
      bf16x8 af = loadB_f32(xrow + kc*32 + quad*8);
#pragma unroll
      for (int nt = 0; nt < 4; nt++)
        acc[nt] = MFMA(af, wfq[kc][nt], acc[nt]);
    }
#pragma unroll
    for (int nt = 0; nt < 4; nt++)
#pragma unroll
      for (int r = 0; r < 4; r++){
        int posr = pt*16 + quad*4 + r;
        tp[(long)posr * NA + nt*16 + m16] = f2bf(acc[nt][r] + btv[nt]);
      }
  }
}

// ---------------------------------------------------------------------------
// Pre-pass 2: pack Wq into bf16 MFMA A-fragment blob.
// ---------------------------------------------------------------------------
__global__ __launch_bounds__(256) void k_pack(
    const float* __restrict__ Wq, unsigned short* __restrict__ blob)
{
  const int lane = threadIdx.x & 63, wv = threadIdx.x >> 6;
  const int m16 = lane & 15, quad = lane >> 4;
#pragma unroll
  for (int kc = 0; kc < 16; kc++){
    bf16x8 t = loadB_f32(Wq + (long)(wv*16 + m16)*NH + kc*32 + quad*8);
    *(bf16x8*)&blob[((wv*16 + kc)*64 + lane)*8] = t;
  }
}

// ---------------------------------------------------------------------------
struct KArgs {
  const int* len;
  const float* bq; const float* v; const float* bv;
  const float* Wih0; const float* Whh0; const float* bih0; const float* bhh0;
  const float* Wih1; const float* Whh1; const float* bih1; const float* bhh1;
  const unsigned short* tp;
  const unsigned short* wqblob;
  u64* hbuf;   // per group: [state*2+par][4096] u64; unit idx(dp,b)=(dp>>2)*64+b*4+(dp&3)
  u64* cbuf;   // per group: [par][half][16 batch][72] u64, unit={seq32,f32}
  float* out;
};

// Poll+stage a 512x16 bf16 h-state into fragment-ordered LDS [kc][lane][8].
// Per-thread: 4 contiguous u64 = one 32B line segment. Detection overlaps
// transfer; exponential backoff keeps retry traffic off the LLC queues.
__device__ __forceinline__ void stage_load(const u64* __restrict__ buf, unsigned sq,
                                           unsigned short (*hs)[64][8], int tid){
  const int lane = tid & 63, wv = tid >> 6;
  const int b = lane & 15, q8 = lane >> 4;
#pragma unroll
  for (int c = 0; c < 4; c++){
    const int kc = wv*4 + c;
    const u64* u0 = buf + (kc*4 + q8)*64 + b*4;
    u64 x0, x1, x2, x3;
    int bk = 0;
    for (;;){
      x0 = aload(u0);     x1 = aload(u0 + 1);
      x2 = aload(u0 + 2); x3 = aload(u0 + 3);
      if ((unsigned)(x0>>32)==sq && (unsigned)(x1>>32)==sq &&
          (unsigned)(x2>>32)==sq && (unsigned)(x3>>32)==sq) break;
      sleep_bk(bk);
      if (bk < 3) bk++;
    }
    u16x8 d;
    d[0]=(unsigned short)x0; d[1]=(unsigned short)(x0>>16);
    d[2]=(unsigned short)x1; d[3]=(unsigned short)(x1>>16);
    d[4]=(unsigned short)x2; d[5]=(unsigned short)(x2>>16);
    d[6]=(unsigned short)x3; d[7]=(unsigned short)(x3>>16);
    *(u16x8*)&hs[kc][lane][0] = d;
  }
}

__global__ __launch_bounds__(256, 1) void k_main(KArgs A_)
{
  const int tid = threadIdx.x, lane = tid & 63, w = tid >> 6;
  const int g = blockIdx.x & 7, m = blockIdx.x >> 3;   // group, member
  const int m16 = lane & 15, quad = lane >> 4;

  __shared__ __attribute__((aligned(16))) unsigned short h0s[16][64][8]; // 16KB
  __shared__ __attribute__((aligned(16))) unsigned short h1s[16][64][8]; // 16KB
  __shared__ __attribute__((aligned(16))) float dslab[6][256];           // gate staging
  __shared__ __attribute__((aligned(16))) float qs[16][68];              // q[b][a]
  __shared__ __attribute__((aligned(16))) float cslab[4][64];            // per-wave ctx partials
  __shared__ float cden[4];
  __shared__ __attribute__((aligned(16))) unsigned short ctxf[64][16];   // scaled ctx B-frags

  u64* hb = A_.hbuf + (long)g * (4*4096);        // [h0 p0|h0 p1|h1 p0|h1 p1]
  u64* cb = A_.cbuf + (long)g * (2*2*16*72);     // [par][half][b][72]
  const int b0 = g * GB;

  // ----- persistent weight fragments (w<3): wf[0..15]=Whh0, [16..31]=Whh1,
  //       [32..47]=Wih1, rows w*512 + m*16 -----
  bf16x8 wf[48], wih0f[2];
  float bhh0v[4], bih0v[4], bhh1v[4], bih1v[4];
  if (w < 3){
    const int r0 = w * NH + m * 16;
#pragma unroll
    for (int kc = 0; kc < 16; kc++){
      wf[kc]    = loadB_f32(A_.Whh0 + (long)(r0 + m16)*NH + kc*32 + quad*8);
      wf[16+kc] = loadB_f32(A_.Whh1 + (long)(r0 + m16)*NH + kc*32 + quad*8);
      wf[32+kc] = loadB_f32(A_.Wih1 + (long)(r0 + m16)*NH + kc*32 + quad*8);
    }
#pragma unroll
    for (int kc = 0; kc < 2; kc++)
      wih0f[kc] = loadB_f32(A_.Wih0 + (r0 + m16)*NA + kc*32 + quad*8);
#pragma unroll
    for (int r = 0; r < 4; r++){
      int d = r0 + quad*4 + r;
      bhh0v[r] = A_.bhh0[d]; bih0v[r] = A_.bih0[d];
      bhh1v[r] = A_.bhh1[d]; bih1v[r] = A_.bih1[d];
    }
  }
  float bqw[4];
#pragma unroll
  for (int r = 0; r < 4; r++) bqw[r] = A_.bq[w*16 + quad*4 + r];

  float vv[16];
#pragma unroll
  for (int jj = 0; jj < 16; jj++) vv[jj] = A_.v[quad*16 + jj];
  const float bvv = A_.bv[0];
  const int ab = m >> 1;            // batch owned by WG pair {2ab, 2ab+1}
  const int wr = (m & 1)*4 + w;     // chunk phase 0..7

  int myidx = 0, imax = 0;
#pragma unroll 1
  for (int b = 0; b < GB; b++){
    int L = A_.len[b0 + b];
    int ix = L - 2; ix = ix < 0 ? 0 : (ix > NT-1 ? NT-1 : ix);
    if (b == m16) myidx = ix;
    imax = imax > ix ? imax : ix;
  }

  f32x4 h0p = {0,0,0,0}, h1p = {0,0,0,0};

  // zero LDS h-state so step 0's matmuls yield pure bias (h(-1)=0)
  {
    u16x8 z = {0,0,0,0,0,0,0,0};
#pragma unroll
    for (int c = 0; c < 4; c++){
      int kc = (tid>>6)*4 + c;
      *(u16x8*)&h0s[kc][lane][0] = z;
      *(u16x8*)&h1s[kc][lane][0] = z;
    }
  }
  __syncthreads();

#pragma unroll 1
  for (int i = 0; i <= imax; i++){
    const int par = i & 1;
    const unsigned sq = (unsigned)(i + 1);

    // ============ Phase A ============
    // w<3: g0 = Whh0 . h0(i-1) + bhh0 FIRST (covers the h1-exchange RT; only
    // w3 polls during the latency window). h0s still holds h0(i-1) here.
    f32x4 g0 = {0,0,0,0};
    if (w < 3){
#pragma unroll
      for (int kc = 0; kc < 16; kc++){
        bf16x8 h0f = *(const bf16x8*)&h0s[kc][lane][0];
        g0 = MFMA(wf[kc], h0f, g0);
      }
#pragma unroll
      for (int r = 0; r < 4; r++) g0[r] += bhh0v[r];
    }
    if (i > 0){
      stage_load(hb + (long)(2 + ((i-1)&1))*4096, (unsigned)i, h1s, tid);
      __syncthreads();
    }
    {
      f32x4 qa = {0,0,0,0};
#pragma unroll
      for (int kc = 0; kc < 16; kc++){
        bf16x8 b1f = *(const bf16x8*)&h1s[kc][lane][0];
        bf16x8 af = *(const bf16x8*)&A_.wqblob[((w*16 + kc)*64 + lane)*8];
        qa = MFMA(af, b1f, qa);
      }
#pragma unroll
      for (int r = 0; r < 4; r++)
        qs[m16][w*16 + quad*4 + r] = qa[r] + bqw[r];
    }
    __syncthreads();   // q ready in LDS

    // ============ Phase B: attention for batch ab, chunk phase wr ============
    {
      float qv[16];
#pragma unroll
      for (int jq = 0; jq < 4; jq++){
        f32x4 t = *(const f32x4*)&qs[ab][quad*16 + jq*4];
        qv[jq*4+0]=t[0]; qv[jq*4+1]=t[1]; qv[jq*4+2]=t[2]; qv[jq*4+3]=t[3];
      }
      float ctxp[16];
#pragma unroll
      for (int jj = 0; jj < 16; jj++) ctxp[jj] = 0.f;
      float denp = 0.f;
      const unsigned short* tpb = A_.tp + (long)(b0 + ab) * NT * NA;
#pragma unroll 1
      for (int c = wr; c*16 <= i; c += 8){
        const int t = c*16 + m16;
        const unsigned short* tpp = tpb + (long)t*NA + quad*16;
        u16x8 ta = *(const u16x8*)tpp;
        u16x8 tb = *(const u16x8*)(tpp + 8);
        float tpf[16];
#pragma unroll
        for (int jj = 0; jj < 8; jj++){ tpf[jj] = bf2f(ta[jj]); tpf[8+jj] = bf2f(tb[jj]); }
        float sp = 0.f;
#pragma unroll
        for (int jj = 0; jj < 16; jj++){
          float x = tpf[jj] + qv[jj];
          sp = fmaf(ftanh(x), vv[jj], sp);
        }
        sp += __shfl_xor(sp, 16);
        sp += __shfl_xor(sp, 32);
        float e = __expf(sp + bvv);
        e = (t <= i) ? e : 0.f;
        denp += e;
#pragma unroll
        for (int jj = 0; jj < 16; jj++) ctxp[jj] = fmaf(e, tpf[jj], ctxp[jj]);
      }
#pragma unroll
      for (int off = 1; off < 64; off <<= 1) denp += __shfl_xor(denp, off);
      denp *= 0.25f;
#pragma unroll
      for (int st = 0; st < 4; st++){
        const int bit = 1 << st;
        const bool up = (lane >> st) & 1;
        const int n2 = (16 >> st) >> 1;
#pragma unroll
        for (int j2 = 0; j2 < 8; j2++){
          if (j2 < n2){
            float keep = up ? ctxp[2*j2+1] : ctxp[2*j2];
            float send = up ? ctxp[2*j2]   : ctxp[2*j2+1];
            float got = __shfl_xor(send, bit);
            ctxp[j2] = keep + got;
          }
        }
      }
      cslab[w][lane] = ctxp[0];
      if (lane == 0) cden[w] = denp;
    }
    __syncthreads();   // 4-wave partials in LDS
    if (w == 0){
      float s = cslab[0][lane] + cslab[1][lane] + cslab[2][lane] + cslab[3][lane];
      u64* slot = cb + ((long)(par*2 + (m & 1))*16 + ab)*72;
      fire(slot + lane, packf(sq, s));
      if (lane == 0)
        fire(slot + 64, packf(sq, cden[0]+cden[1]+cden[2]+cden[3]));
    }

    // ============ Phase C: w3 polls ctx (sole poller); w<3 wait ============
    if (w == 3){
      const u64* c0 = cb + ((long)(par*2 + 0)*16 + m16)*72;
      const u64* c1 = cb + ((long)(par*2 + 1)*16 + m16)*72;
      u64 d0, d1;
      {
        int bk = 0;
        for (;;){
          d0 = aload(c0 + 64); d1 = aload(c1 + 64);
          if ((unsigned)(d0>>32)==sq && (unsigned)(d1>>32)==sq) break;
          sleep_bk(bk);
          if (bk < 3) bk++;
        }
      }
      const float rdn = __builtin_amdgcn_rcpf(
          __builtin_bit_cast(float,(unsigned)d0) + __builtin_bit_cast(float,(unsigned)d1));
#pragma unroll
      for (int kc = 0; kc < 2; kc++){
        const int a0 = kc*32 + quad*8;
        u64 t0[8], t1[8];
        int bk = 0;
        for (;;){
          bool ok = true;
#pragma unroll
          for (int j = 0; j < 8; j++){ t0[j] = aload(c0 + a0 + j); ok &= ((unsigned)(t0[j]>>32)==sq); }
#pragma unroll
          for (int j = 0; j < 8; j++){ t1[j] = aload(c1 + a0 + j); ok &= ((unsigned)(t1[j]>>32)==sq); }
          if (ok) break;
          sleep_bk(bk);
          if (bk < 3) bk++;
        }
        u16x8 f;
#pragma unroll
        for (int j = 0; j < 8; j++){
          float s = (__builtin_bit_cast(float,(unsigned)t0[j]) +
                     __builtin_bit_cast(float,(unsigned)t1[j])) * rdn;
          f[j] = f2bf(s);
        }
        *(u16x8*)&ctxf[lane][kc*8] = f;
      }
    }
    __syncthreads();   // ctx frags ready
    if (w < 3){
      f32x4 gi0 = {0,0,0,0};
      bf16x8 cf0 = *(const bf16x8*)&ctxf[lane][0];
      bf16x8 cf1 = *(const bf16x8*)&ctxf[lane][8];
      gi0 = MFMA(wih0f[0], cf0, gi0);
      gi0 = MFMA(wih0f[1], cf1, gi0);
#pragma unroll
      for (int r = 0; r < 4; r++) gi0[r] += bih0v[r];
      *(f32x4*)&dslab[w][lane*4] = g0;
      *(f32x4*)&dslab[3+w][lane*4] = gi0;
    }
    __syncthreads();
    if (w == 3){
      f32x4 ghr = *(f32x4*)&dslab[0][lane*4];
      f32x4 ghz = *(f32x4*)&dslab[1][lane*4];
      f32x4 ghn = *(f32x4*)&dslab[2][lane*4];
      f32x4 gir = *(f32x4*)&dslab[3][lane*4];
      f32x4 giz = *(f32x4*)&dslab[4][lane*4];
      f32x4 gin = *(f32x4*)&dslab[5][lane*4];
      f32x4 hn;
#pragma unroll
      for (int r = 0; r < 4; r++){
        float rr = fsig(gir[r] + ghr[r]);
        float zz = fsig(giz[r] + ghz[r]);
        float nn = ftanh(gin[r] + rr*ghn[r]);
        hn[r] = (1.f - zz)*nn + zz*h0p[r];
      }
      h0p = hn;
      const int dp0 = m*8 + quad*2;
      u64* p0 = hb + (long)par*4096 + (dp0>>2)*64 + m16*4 + (dp0&3);
      fire(p0,     packh(sq, hn[0], hn[1]));
      fire(p0 + 1, packh(sq, hn[2], hn[3]));
    }

    // ============ Phase D ============
    // w<3: gh1 = Whh1 . h1(i-1) + bhh1 FIRST (covers the h0-exchange RT;
    // w3 fires h0 then polls alone while w<3 run MFMAs, then join staging).
    f32x4 gh1 = {0,0,0,0};
    if (w < 3){
#pragma unroll
      for (int kc = 0; kc < 16; kc++){
        bf16x8 b1f = *(const bf16x8*)&h1s[kc][lane][0];
        gh1 = MFMA(wf[16+kc], b1f, gh1);
      }
#pragma unroll
      for (int r = 0; r < 4; r++) gh1[r] += bhh1v[r];
    }
    stage_load(hb + (long)par*4096, sq, h0s, tid);
    __syncthreads();
    if (w < 3){
      f32x4 gi1 = {0,0,0,0};
#pragma unroll
      for (int kc = 0; kc < 16; kc++){
        bf16x8 hf = *(const bf16x8*)&h0s[kc][lane][0];
        gi1 = MFMA(wf[32+kc], hf, gi1);
      }
#pragma unroll
      for (int r = 0; r < 4; r++) gi1[r] += bih1v[r];
      *(f32x4*)&dslab[w][lane*4] = gh1;
      *(f32x4*)&dslab[3+w][lane*4] = gi1;
    }
    __syncthreads();
    if (w == 3){
      f32x4 ghr = *(f32x4*)&dslab[0][lane*4];
      f32x4 ghz = *(f32x4*)&dslab[1][lane*4];
      f32x4 ghn = *(f32x4*)&dslab[2][lane*4];
      f32x4 gir = *(f32x4*)&dslab[3][lane*4];
      f32x4 giz = *(f32x4*)&dslab[4][lane*4];
      f32x4 gin = *(f32x4*)&dslab[5][lane*4];
      f32x4 hn;
#pragma unroll
      for (int r = 0; r < 4; r++){
        float rr = fsig(gir[r] + ghr[r]);
        float zz = fsig(giz[r] + ghz[r]);
        float nn = ftanh(gin[r] + rr*ghn[r]);
        hn[r] = (1.f - zz)*nn + zz*h1p[r];
      }
      h1p = hn;
      const int dp0 = m*8 + quad*2;
      u64* p1 = hb + (long)(2 + par)*4096 + (dp0>>2)*64 + m16*4 + (dp0&3);
      fire(p1,     packh(sq, hn[0], hn[1]));
      fire(p1 + 1, packh(sq, hn[2], hn[3]));
      if (i == myidx)
        *(f32x4*)&A_.out[(long)(b0 + m16)*NH + m*16 + quad*4] = hn;
    }
  }
}

// ---------------------------------------------------------------------------
extern "C" void kernel_launch(void* const* d_in, const int* in_sizes, int n_in,
                              void* d_out, int out_size, void* d_ws, size_t ws_size,
                              hipStream_t stream)
{
  (void)in_sizes; (void)n_in; (void)out_size; (void)ws_size;
  char* ws = (char*)d_ws;
  unsigned short* tp     = (unsigned short*)ws;                    // 8 MB
  unsigned short* wqblob = (unsigned short*)(ws + 8388608);        // 64 KB
  u64* hbuf = (u64*)(ws + 8388608 + 65536);                        // 1 MB
  u64* cbuf = hbuf + 8 * (4*4096);                                 // 288 KB

  // 0xFF-fill all seq-tagged slots: tag 0xFFFFFFFF never matches a target
  // seq (<= 513), so garbage/stale data can never be accepted by a poll.
  (void)hipMemsetAsync(hbuf, 0xFF, (size_t)(8*4*4096 + 8*2*2*16*72) * sizeof(u64), stream);

  k_tp<<<dim3(256), dim3(256), 0, stream>>>(
      (const int*)d_in[0], (const float*)d_in[2], (const float*)d_in[3],
      (const float*)d_in[4], tp);
  k_pack<<<dim3(1), dim3(256), 0, stream>>>((const float*)d_in[5], wqblob);

  KArgs ka;
  ka.len  = (const int*)d_in[1];
  ka.bq   = (const float*)d_in[6];
  ka.v    = (const float*)d_in[7];  ka.bv   = (const float*)d_in[8];
  ka.Wih0 = (const float*)d_in[9];  ka.Whh0 = (const float*)d_in[10];
  ka.bih0 = (const float*)d_in[11]; ka.bhh0 = (const float*)d_in[12];
  ka.Wih1 = (const float*)d_in[13]; ka.Whh1 = (const float*)d_in[14];
  ka.bih1 = (const float*)d_in[15]; ka.bhh1 = (const float*)d_in[16];
  ka.tp = tp; ka.wqblob = wqblob;
  ka.hbuf = hbuf; ka.cbuf = cbuf;
  ka.out = (float*)d_out;

  k_main<<<dim3(256), dim3(256), 0, stream>>>(ka);
}